// Round 6
// baseline (385.084 us; speedup 1.0000x reference)
//
#include <hip/hip_runtime.h>

typedef __attribute__((ext_vector_type(8))) short short8;
typedef __attribute__((ext_vector_type(4))) float floatx4;

__device__ __forceinline__ unsigned short bf16_rne(float f) {
  unsigned int u = __builtin_bit_cast(unsigned int, f);
  u += 0x7fffu + ((u >> 16) & 1u);
  return (unsigned short)(u >> 16);
}

__device__ __forceinline__ void glds16(const void* g, void* l) {
  __builtin_amdgcn_global_load_lds((const __attribute__((address_space(1))) void*)g,
                                   (__attribute__((address_space(3))) void*)l, 16, 0, 0);
}

// xpad layout: [b][kc 8][pos 3364 = 58*58][cil 32] bf16  (chunk-major, glds-contiguous)
// agg  layout: [b][kc 8][rs 9][co 256][cil 32] bf16      (A-slab coalesced per-wave reads)

// ---------------- zero pooledk (32x4 floats of pre-dot attention sums) ----------------
__global__ void zero_pk_kernel(float* __restrict__ pk) {
  pk[threadIdx.x] = 0.f;
}

// ---------------- prep: transpose+cast x into xpad; fused att-dot; fused border zero ----------------
__global__ __launch_bounds__(256) void prep_kernel(const float* __restrict__ x,
                                                   const float* __restrict__ att_w,
                                                   unsigned short* __restrict__ xpad,
                                                   float* __restrict__ pooledk) {
  const int bid = blockIdx.x;          // 32 b x 4 cig x 49 spc
  const int b   = bid / 196;
  const int rem = bid - b * 196;
  const int cig = rem / 49;
  const int spc = rem - cig * 49;
  const int t  = threadIdx.x;
  const int cs = t >> 6, sl = t & 63;
  const int sp0 = spc * 64;

  __shared__ unsigned short T2[64 * 72];   // [sp 64][ci 64], pitch 72 ush (b128-aligned, bank-balanced)
  __shared__ float red[4][4];

  // 16 coalesced row loads (256B per instr), kept in registers
  const float* xrow = x + (size_t)(b * 256 + cig * 64 + cs * 16) * 3136 + sp0 + sl;
  float v[16];
  #pragma unroll
  for (int i = 0; i < 16; ++i) v[i] = xrow[(size_t)i * 3136];

  // attention partial: per-lane dot first (linear), then ONE 4-acc butterfly reduce
  float acc0 = 0.f, acc1 = 0.f, acc2 = 0.f, acc3 = 0.f;
  #pragma unroll
  for (int i = 0; i < 16; ++i) {
    const int ci = cig * 64 + cs * 16 + i;
    acc0 += v[i] * att_w[0 * 256 + ci];
    acc1 += v[i] * att_w[1 * 256 + ci];
    acc2 += v[i] * att_w[2 * 256 + ci];
    acc3 += v[i] * att_w[3 * 256 + ci];
  }
  #pragma unroll
  for (int o = 32; o > 0; o >>= 1) {
    acc0 += __shfl_xor(acc0, o, 64);
    acc1 += __shfl_xor(acc1, o, 64);
    acc2 += __shfl_xor(acc2, o, 64);
    acc3 += __shfl_xor(acc3, o, 64);
  }
  if (sl == 0) { red[cs][0] = acc0; red[cs][1] = acc1; red[cs][2] = acc2; red[cs][3] = acc3; }

  // transpose: pack 16 consecutive-ci bf16 into two b128 LDS writes
  short8 w0, w1;
  #pragma unroll
  for (int i = 0; i < 8; ++i) w0[i] = (short)bf16_rne(v[i]);
  #pragma unroll
  for (int i = 0; i < 8; ++i) w1[i] = (short)bf16_rne(v[8 + i]);
  *(short8*)(T2 + sl * 72 + cs * 16) = w0;
  *(short8*)(T2 + sl * 72 + cs * 16 + 8) = w1;
  __syncthreads();

  if (t < 4) {
    float s = red[0][t] + red[1][t] + red[2][t] + red[3][t];
    atomicAdd(&pooledk[b * 4 + t], s);      // 4 atomics per block total
  }

  // xpad write, re-enumerated for contiguity: task (kcsel, spl, o2) so each wave
  // writes ~1KB contiguous runs (16 consecutive pos x 4 o2 = 64B x 16).
  unsigned short* xb = xpad + (size_t)b * (8 * 3364 * 32);
  #pragma unroll
  for (int it = 0; it < 2; ++it) {
    const int c9 = it * 256 + t;             // 0..511
    const int o2 = c9 & 3, spl = (c9 >> 2) & 63, kcsel = c9 >> 8;
    const int kc = cig * 2 + kcsel;
    const int spg = sp0 + spl;
    const int h = spg / 56, wc = spg - h * 56;
    const int pos = (h + 1) * 58 + (wc + 1);
    const short8 vv = *(const short8*)(T2 + spl * 72 + (kcsel * 4 + o2) * 8);
    *(short8*)(xb + (size_t)kc * (3364 * 32) + pos * 32 + o2 * 8) = vv;
  }

  // fused border zeroing: 4 designated blocks per b (cig==0, spc<4), quarter = spc
  if (cig == 0 && spc < 4) {
    const short8 z = {0, 0, 0, 0, 0, 0, 0, 0};
    #pragma unroll
    for (int it = 0; it < 8; ++it) {
      const int idx = it * 256 + t;               // 57 pos x 8 kc x 4 chunks = 1824
      if (idx >= 1824) break;
      const int s8 = idx & 3, kc = (idx >> 2) & 7, j = idx >> 5;
      const int pi = spc * 57 + j;
      int h2, w2;
      if (pi < 58)       { h2 = 0;  w2 = pi; }
      else if (pi < 116) { h2 = 57; w2 = pi - 58; }
      else { const int k = pi - 116; h2 = 1 + (k >> 1); w2 = (k & 1) * 57; }
      *(short8*)(xb + (size_t)kc * (3364 * 32) + (h2 * 58 + w2) * 32 + s8 * 8) = z;
    }
  }
}

// ---------------- agg: (co, b-quarter) grid; sigmoid fused; packed short8 stores ----------------
__global__ __launch_bounds__(256) void agg_kernel(const float* __restrict__ w,
                                                  const float* __restrict__ pooledk,
                                                  unsigned short* __restrict__ agg) {
  const int co = blockIdx.x;     // 256
  const int bq = blockIdx.y;     // 8 quarters of 4 b each
  const int t = threadIdx.x;
  __shared__ float W[4][2304];
  __shared__ float attl[16];     // sigmoid(att) for 4 b x 4 experts
  if (t < 16) {
    const float z = pooledk[bq * 16 + t] * (1.f / 3136.f);
    attl[t] = 1.f / (1.f + expf(-z));
  }
  #pragma unroll
  for (int e = 0; e < 4; ++e) {
    const float* src = w + (size_t)(e * 256 + co) * 2304;
    #pragma unroll
    for (int j = 0; j < 9; ++j) W[e][j * 256 + t] = src[j * 256 + t];
  }
  __syncthreads();

  // 288 short8-tasks per b: (kc 8, rs 9, oct 4). Thread t does task t (+ t+256 if t<32).
  #pragma unroll
  for (int rep = 0; rep < 2; ++rep) {
    const int id = rep * 256 + t;
    if (id < 288) {
      const int kc  = id / 36;
      const int rm  = id - kc * 36;
      const int rs  = rm >> 2;
      const int oct = rm & 3;
      const int wib = (kc * 32 + oct * 8) * 9 + rs;               // W idx: ci*9 + rs
      const int off = (kc * 9 + rs) * 8192 + co * 32 + oct * 8;   // agg offset within b
      float w0[8], w1[8], w2[8], w3[8];
      #pragma unroll
      for (int u = 0; u < 8; ++u) {
        w0[u] = W[0][wib + u * 9];
        w1[u] = W[1][wib + u * 9];
        w2[u] = W[2][wib + u * 9];
        w3[u] = W[3][wib + u * 9];
      }
      #pragma unroll
      for (int bl = 0; bl < 4; ++bl) {
        const int b = bq * 4 + bl;
        const float a0 = attl[bl * 4 + 0], a1 = attl[bl * 4 + 1];
        const float a2 = attl[bl * 4 + 2], a3 = attl[bl * 4 + 3];
        short8 vv;
        #pragma unroll
        for (int u = 0; u < 8; ++u)
          vv[u] = (short)bf16_rne(a0 * w0[u] + a1 * w1[u] + a2 * w2[u] + a3 * w3[u]);
        *(short8*)(agg + (size_t)b * 589824 + off) = vv;
      }
    }
  }
}

// ---------------- conv: implicit GEMM, 128co x 128p; depth-3 A reg-prefetch, B dbuf LDS.
// All vmem ops UNCONDITIONAL (Bsm padded to 384 rows; xnxt wraps at kc=7; A slice clamped)
// so the compiler can compute exact counted vmcnt waits. kc boundary uses
// s_waitcnt vmcnt(12) + raw s_barrier: the 12 cross-kc A-prefetch loads stay in flight,
// all B staging DMA provably drained. Never vmcnt(0) in the main loop (T4).
__global__ __launch_bounds__(256, 3) void conv_kernel(const unsigned short* __restrict__ xpad,
                                                      const unsigned short* __restrict__ aggw,
                                                      float* __restrict__ out) {
  __shared__ alignas(16) unsigned short Bsm[2][384 * 32];   // 2 x 24576 B = 49152 -> 3 blocks/CU

  const int t  = threadIdx.x;
  // XCD-aware bijective swizzle: 1600 blocks, 8 XCDs -> each XCD owns 4 consecutive b's
  const int bx0 = blockIdx.x;
  const int bx  = (bx0 & 7) * 200 + (bx0 >> 3);
  const int p_t  = bx % 25;
  const int co_t = (bx / 25) & 1;
  const int b    = bx / 50;
  const int p0   = p_t * 128;
  const int oh_min = p0 / 56;

  const unsigned short* xb  = xpad + (size_t)b * (8 * 3364 * 32);
  const unsigned short* awb = aggw + (size_t)b * 589824 + co_t * 4096;

  const int lane = t & 63;
  const int wv = t >> 6;
  const int wm = wv >> 1;                   // co half
  const int wn = wv & 1;                    // p half
  const int m16 = lane & 15;
  const int q = lane >> 4;

  int aoff[4], brow[4];
  #pragma unroll
  for (int i = 0; i < 4; ++i)
    aoff[i] = (wm * 64 + i * 16 + m16) * 32 + q * 8;
  #pragma unroll
  for (int j = 0; j < 4; ++j) {
    const int pf = p0 + wn * 64 + j * 16 + m16;
    const int oh = pf / 56;
    const int ow = pf - oh * 56;
    brow[j] = ((oh - oh_min) * 58 + ow) * 32 + q * 8;
  }

  // B staging offsets: 6 full pieces (384*4 = 1536 chunks), all lanes active, clamped rows
  int bofO[6];
  #pragma unroll
  for (int i = 0; i < 6; ++i) {
    const int c = i * 256 + t;
    const int pos = c >> 2, sub = c & 3;
    const int prow = pos / 58, pcol = pos - prow * 58;
    int ih2 = oh_min + prow; if (ih2 > 57) ih2 = 57;   // clamp (dup/garbage rows unused)
    bofO[i] = (ih2 * 58 + pcol) * 32 + sub * 8;
  }

  floatx4 acc[4][4];
  #pragma unroll
  for (int i = 0; i < 4; ++i)
    #pragma unroll
    for (int j = 0; j < 4; ++j)
      acc[i][j] = (floatx4){0.f, 0.f, 0.f, 0.f};

  // prologue: stage B(kc=0) whole; A slices 0..2 into the register pipeline
  #pragma unroll
  for (int i = 0; i < 6; ++i)
    glds16(xb + bofO[i], (void*)(Bsm[0] + (i * 256 + t) * 8));
  short8 af0[4], af1[4], af2[4];
  #pragma unroll
  for (int i = 0; i < 4; ++i) af0[i] = *(const short8*)(awb + (size_t)0 * 8192 + aoff[i]);
  #pragma unroll
  for (int i = 0; i < 4; ++i) af1[i] = *(const short8*)(awb + (size_t)1 * 8192 + aoff[i]);
  #pragma unroll
  for (int i = 0; i < 4; ++i) af2[i] = *(const short8*)(awb + (size_t)2 * 8192 + aoff[i]);
  asm volatile("s_waitcnt vmcnt(12)" ::: "memory");   // B landed; 12 A loads in flight
  __builtin_amdgcn_s_barrier();
  __builtin_amdgcn_sched_barrier(0);

  for (int kc = 0; kc < 8; ++kc) {
    const unsigned short* Bcur = Bsm[kc & 1];
    unsigned short* Bnxt = Bsm[(kc + 1) & 1];
    const unsigned short* xnxt = xb + (size_t)((kc + 1) & 7) * (3364 * 32);  // kc=7 wraps: staged, never read

    #pragma unroll
    for (int rs = 0; rs < 9; ++rs) {
      // 1) A prefetch, 3 slices ahead (clamped at the tail; dup loads unused)
      int pfs = kc * 9 + rs + 3; if (pfs > 71) pfs = 71;
      short8 afN[4];
      #pragma unroll
      for (int i = 0; i < 4; ++i)
        afN[i] = *(const short8*)(awb + (size_t)pfs * 8192 + aoff[i]);
      __builtin_amdgcn_sched_barrier(0);
      // 2) one B DMA piece for kc+1 (after A issues -> A waits never drain B early)
      if (rs < 6)
        glds16(xnxt + bofO[rs], (void*)(Bnxt + (rs * 256 + t) * 8));
      __builtin_amdgcn_sched_barrier(0);

      // 3) compute current slice (af0 = slice kc*9+rs, loaded 3 iterations ago)
      const int r = rs / 3, s = rs - r * 3;
      const int d = (r * 58 + s) * 32;
      short8 bfr[4];
      #pragma unroll
      for (int j = 0; j < 4; ++j)
        bfr[j] = *(const short8*)(Bcur + brow[j] + d);
      __builtin_amdgcn_s_setprio(1);
      #pragma unroll
      for (int i = 0; i < 4; ++i)
        #pragma unroll
        for (int j = 0; j < 4; ++j)
          acc[i][j] = __builtin_amdgcn_mfma_f32_16x16x32_bf16(af0[i], bfr[j], acc[i][j], 0, 0, 0);
      __builtin_amdgcn_s_setprio(0);

      // rotate pipeline (fully unrolled -> register renaming, no moves)
      #pragma unroll
      for (int i = 0; i < 4; ++i) { af0[i] = af1[i]; af1[i] = af2[i]; af2[i] = afN[i]; }
    }
    // kc boundary: all 6 B pieces done (12 newer A loads stay in flight)
    asm volatile("s_waitcnt vmcnt(12)" ::: "memory");
    __builtin_amdgcn_s_barrier();
    __builtin_amdgcn_sched_barrier(0);
  }

  // ---- epilogue: D col = lane&15 (p), row = q*4+reg (co) ----
  #pragma unroll
  for (int i = 0; i < 4; ++i) {
    const int co = co_t * 128 + wm * 64 + i * 16 + q * 4;
    float* orow = out + (size_t)(b * 256 + co) * 3136;
    #pragma unroll
    for (int j = 0; j < 4; ++j) {
      const int pp = p0 + wn * 64 + j * 16 + m16;
      if (pp < 3136) {
        #pragma unroll
        for (int rg = 0; rg < 4; ++rg)
          orow[(size_t)rg * 3136 + pp] = acc[i][j][rg];
      }
    }
  }
}

extern "C" void kernel_launch(void* const* d_in, const int* in_sizes, int n_in,
                              void* d_out, int out_size, void* d_ws, size_t ws_size,
                              hipStream_t stream) {
  const float* x      = (const float*)d_in[0];   // (32,256,56,56)
  const float* att_w  = (const float*)d_in[1];   // (4,256)
  const float* weight = (const float*)d_in[2];   // (4,256,256,3,3)
  float* out = (float*)d_out;                    // (32,256,56,56)

  char* ws = (char*)d_ws;
  float* pooledk       = (float*)ws;                                // 512 B (pre-dot sums)
  unsigned short* agg  = (unsigned short*)(ws + 65536);             // 37,748,736 B
  unsigned short* xpad = (unsigned short*)(ws + 65536 + 37748736);  // 55,115,776 B

  zero_pk_kernel<<<1, 128, 0, stream>>>(pooledk);
  prep_kernel<<<6272, 256, 0, stream>>>(x, att_w, xpad, pooledk);
  agg_kernel<<<dim3(256, 8), 256, 0, stream>>>(weight, pooledk, agg);
  conv_kernel<<<1600, 256, 0, stream>>>(xpad, agg, out);
}

// Round 8
// 302.374 us; speedup vs baseline: 1.2735x; 1.2735x over previous
//
#include <hip/hip_runtime.h>

typedef __attribute__((ext_vector_type(8))) short short8;
typedef __attribute__((ext_vector_type(4))) float floatx4;
typedef __attribute__((ext_vector_type(4))) unsigned short ush4;

__device__ __forceinline__ unsigned short bf16_rne(float f) {
  unsigned int u = __builtin_bit_cast(unsigned int, f);
  u += 0x7fffu + ((u >> 16) & 1u);
  return (unsigned short)(u >> 16);
}

__device__ __forceinline__ void glds16(const void* g, void* l) {
  __builtin_amdgcn_global_load_lds((const __attribute__((address_space(1))) void*)g,
                                   (__attribute__((address_space(3))) void*)l, 16, 0, 0);
}

// xpad layout: [b][kc 8][pos 3364 = 58*58][cil 32] bf16  (chunk-major, glds-contiguous)
// agg  layout: [b][kc 8][rs 9][co 256][cil 32] bf16      (A-slab glds-contiguous)
// pooledk: padded stride 16 floats (one cache line per (b,k)) to kill atomic false sharing

// ---------------- zero pooledk (128 padded slots) ----------------
__global__ void zero_pk_kernel(float* __restrict__ pk) {
  #pragma unroll
  for (int i = 0; i < 8; ++i) pk[i * 256 + threadIdx.x] = 0.f;
}

// ---------------- prep: transpose+cast x into xpad; fused att-dot; fused border zero ----------------
__global__ __launch_bounds__(256) void prep_kernel(const float* __restrict__ x,
                                                   const float* __restrict__ att_w,
                                                   unsigned short* __restrict__ xpad,
                                                   float* __restrict__ pooledk) {
  const int bid = blockIdx.x;          // 32 b x 4 cig x 49 spc
  const int b   = bid / 196;
  const int rem = bid - b * 196;
  const int cig = rem / 49;
  const int spc = rem - cig * 49;
  const int t  = threadIdx.x;
  const int cs = t >> 6, sl = t & 63;
  const int sp0 = spc * 64;

  __shared__ unsigned short T2[64 * 72];   // [sp 64][ci 64], pitch 72 ush (bank-staggered)
  __shared__ float red[4][4];

  // float4 loads: 4 instrs per thread cover 16 rows x 64 sp for the wave
  const int qd = sl >> 4;                  // row sub-block 0..3
  const int sx = sl & 15;                  // sp quad 0..15
  const float* xrow = x + (size_t)(b * 256 + cig * 64 + cs * 16 + qd * 4) * 3136 + sp0 + sx * 4;
  floatx4 v4[4];
  #pragma unroll
  for (int i = 0; i < 4; ++i) v4[i] = *(const floatx4*)(xrow + (size_t)i * 3136);

  // attention partial: per-thread 4-wide sp sums, tiny dot, ONE 4-acc butterfly reduce
  float acc0 = 0.f, acc1 = 0.f, acc2 = 0.f, acc3 = 0.f;
  #pragma unroll
  for (int i = 0; i < 4; ++i) {
    const float sv = v4[i][0] + v4[i][1] + v4[i][2] + v4[i][3];
    const float* aw = att_w + (cig * 64 + cs * 16 + qd * 4 + i);
    acc0 += sv * aw[0];
    acc1 += sv * aw[256];
    acc2 += sv * aw[512];
    acc3 += sv * aw[768];
  }
  #pragma unroll
  for (int o = 32; o > 0; o >>= 1) {
    acc0 += __shfl_xor(acc0, o, 64);
    acc1 += __shfl_xor(acc1, o, 64);
    acc2 += __shfl_xor(acc2, o, 64);
    acc3 += __shfl_xor(acc3, o, 64);
  }
  if (sl == 0) { red[cs][0] = acc0; red[cs][1] = acc1; red[cs][2] = acc2; red[cs][3] = acc3; }

  // transpose: each thread writes 4 b64 (4 sp x 4 contiguous ci)
  #pragma unroll
  for (int s = 0; s < 4; ++s) {
    ush4 wv;
    wv[0] = bf16_rne(v4[0][s]);
    wv[1] = bf16_rne(v4[1][s]);
    wv[2] = bf16_rne(v4[2][s]);
    wv[3] = bf16_rne(v4[3][s]);
    *(ush4*)(T2 + (sx * 4 + s) * 72 + cs * 16 + qd * 4) = wv;
  }
  __syncthreads();

  if (t < 4) {
    float s = red[0][t] + red[1][t] + red[2][t] + red[3][t];
    atomicAdd(&pooledk[(b * 4 + t) * 16], s);   // padded: one line per (b,k), no false sharing
  }

  // xpad write: contiguous task enumeration (kcsel, spl, o2); ~1KB runs per wave
  unsigned short* xb = xpad + (size_t)b * (8 * 3364 * 32);
  #pragma unroll
  for (int it = 0; it < 2; ++it) {
    const int c9 = it * 256 + t;             // 0..511
    const int o2 = c9 & 3, spl = (c9 >> 2) & 63, kcsel = c9 >> 8;
    const int kc = cig * 2 + kcsel;
    const int spg = sp0 + spl;
    const int h = spg / 56, wc = spg - h * 56;
    const int pos = (h + 1) * 58 + (wc + 1);
    const short8 vv = *(const short8*)(T2 + spl * 72 + (kcsel * 4 + o2) * 8);
    *(short8*)(xb + (size_t)kc * (3364 * 32) + pos * 32 + o2 * 8) = vv;
  }

  // fused border zeroing: 4 designated blocks per b (cig==0, spc<4), quarter = spc
  if (cig == 0 && spc < 4) {
    const short8 z = {0, 0, 0, 0, 0, 0, 0, 0};
    #pragma unroll
    for (int it = 0; it < 8; ++it) {
      const int idx = it * 256 + t;               // 57 pos x 8 kc x 4 chunks = 1824
      if (idx >= 1824) break;
      const int s8 = idx & 3, kc = (idx >> 2) & 7, j = idx >> 5;
      const int pi = spc * 57 + j;
      int h2, w2;
      if (pi < 58)       { h2 = 0;  w2 = pi; }
      else if (pi < 116) { h2 = 57; w2 = pi - 58; }
      else { const int k = pi - 116; h2 = 1 + (k >> 1); w2 = (k & 1) * 57; }
      *(short8*)(xb + (size_t)kc * (3364 * 32) + (h2 * 58 + w2) * 32 + s8 * 8) = z;
    }
  }
}

// ---------------- agg: (co, b-quarter) grid; sigmoid fused; packed short8 stores ----------------
__global__ __launch_bounds__(256) void agg_kernel(const float* __restrict__ w,
                                                  const float* __restrict__ pooledk,
                                                  unsigned short* __restrict__ agg) {
  const int co = blockIdx.x;     // 256
  const int bq = blockIdx.y;     // 8 quarters of 4 b each
  const int t = threadIdx.x;
  __shared__ float W[4][2304];
  __shared__ float attl[16];     // sigmoid(att) for 4 b x 4 experts
  if (t < 16) {
    const float z = pooledk[(bq * 16 + t) * 16] * (1.f / 3136.f);
    attl[t] = 1.f / (1.f + expf(-z));
  }
  #pragma unroll
  for (int e = 0; e < 4; ++e) {
    const float* src = w + (size_t)(e * 256 + co) * 2304;
    #pragma unroll
    for (int j = 0; j < 9; ++j) W[e][j * 256 + t] = src[j * 256 + t];
  }
  __syncthreads();

  // 288 short8-tasks per b: (kc 8, rs 9, oct 4). Thread t does task t (+ t+256 if t<32).
  #pragma unroll
  for (int rep = 0; rep < 2; ++rep) {
    const int id = rep * 256 + t;
    if (id < 288) {
      const int kc  = id / 36;
      const int rm  = id - kc * 36;
      const int rs  = rm >> 2;
      const int oct = rm & 3;
      const int wib = (kc * 32 + oct * 8) * 9 + rs;               // W idx: ci*9 + rs
      const int off = (kc * 9 + rs) * 8192 + co * 32 + oct * 8;   // agg offset within b
      float w0[8], w1[8], w2[8], w3[8];
      #pragma unroll
      for (int u = 0; u < 8; ++u) {
        w0[u] = W[0][wib + u * 9];
        w1[u] = W[1][wib + u * 9];
        w2[u] = W[2][wib + u * 9];
        w3[u] = W[3][wib + u * 9];
      }
      #pragma unroll
      for (int bl = 0; bl < 4; ++bl) {
        const int b = bq * 4 + bl;
        const float a0 = attl[bl * 4 + 0], a1 = attl[bl * 4 + 1];
        const float a2 = attl[bl * 4 + 2], a3 = attl[bl * 4 + 3];
        short8 vv;
        #pragma unroll
        for (int u = 0; u < 8; ++u)
          vv[u] = (short)bf16_rne(a0 * w0[u] + a1 * w1[u] + a2 * w2[u] + a3 * w3[u]);
        *(short8*)(agg + (size_t)b * 589824 + off) = vv;
      }
    }
  }
}

// ---------------- conv: round-1 structure (verbatim): implicit GEMM, 128co x 128p,
// 3-rs A groups staged via glds, 48 MFMA per barrier window, XCD-swizzled ----------------
__global__ __launch_bounds__(256) void conv_kernel(const unsigned short* __restrict__ xpad,
                                                   const unsigned short* __restrict__ aggw,
                                                   float* __restrict__ out) {
  __shared__ unsigned short Bsm[348 * 32];       // 22272 B: [local pos][cil 32]
  __shared__ unsigned short Asm[3 * 128 * 32];   // 24576 B: [rsl][co 128][k 32]

  const int t  = threadIdx.x;
  const int bx0 = blockIdx.x;
  const int bx  = (bx0 & 7) * 200 + (bx0 >> 3);
  const int p_t  = bx % 25;
  const int co_t = (bx / 25) & 1;
  const int b    = bx / 50;
  const int p0   = p_t * 128;
  const int oh_min = p0 / 56;

  const unsigned short* xb  = xpad + (size_t)b * (8 * 3364 * 32);
  const unsigned short* awb = aggw + (size_t)b * 589824 + co_t * 4096;

  const int lane = t & 63;
  const int wv = t >> 6;
  const int wm = wv >> 1;                   // co half
  const int wn = wv & 1;                    // p half
  const int m16 = lane & 15;
  const int q = lane >> 4;

  int aoff[4], boff[4];
  #pragma unroll
  for (int i = 0; i < 4; ++i)
    aoff[i] = (wm * 64 + i * 16 + m16) * 32 + q * 8;
  #pragma unroll
  for (int j = 0; j < 4; ++j) {
    const int pf = p0 + wn * 64 + j * 16 + m16;
    const int oh = pf / 56;
    const int ow = pf - oh * 56;
    boff[j] = ((oh - oh_min) * 58 + ow) * 32 + q * 8;
  }

  floatx4 acc[4][4];
  #pragma unroll
  for (int i = 0; i < 4; ++i)
    #pragma unroll
    for (int j = 0; j < 4; ++j)
      acc[i][j] = (floatx4){0.f, 0.f, 0.f, 0.f};

  for (int kc = 0; kc < 8; ++kc) {
    const unsigned short* xkc = xb + (size_t)kc * (3364 * 32);
    // ---- stage B x-tile: 348 pos x 32 ci, contiguous glds ----
    #pragma unroll
    for (int i = 0; i < 6; ++i) {
      const int c = i * 256 + t;
      if (c < 1392) {
        const int pos = c >> 2, sub = c & 3;
        const int prow = pos / 58;
        const int pcol = pos - prow * 58;
        int ih2 = oh_min + prow; if (ih2 > 57) ih2 = 57;   // clamp (dup rows unused)
        glds16(xkc + ((size_t)(ih2 * 58 + pcol) * 32 + sub * 8), (void*)(Bsm + c * 8));
      }
    }
    #pragma unroll
    for (int g = 0; g < 3; ++g) {
      // ---- stage A: 3 rs-slices (r = g, s = 0..2), contiguous per slice ----
      #pragma unroll
      for (int i = 0; i < 6; ++i) {
        const int c = i * 256 + t;
        const int rsl = c >> 9;
        const int w5 = c & 511;
        glds16(awb + (size_t)(kc * 9 + g * 3 + rsl) * 8192 + w5 * 8, (void*)(Asm + c * 8));
      }
      __syncthreads();   // drains glds + barrier

      #pragma unroll
      for (int rsl = 0; rsl < 3; ++rsl) {
        const int d = (g * 58 + rsl) * 32;     // shift: r = g, s = rsl
        short8 af[4], bf[4];
        #pragma unroll
        for (int i = 0; i < 4; ++i)
          af[i] = *(const short8*)(Asm + rsl * 4096 + aoff[i]);
        #pragma unroll
        for (int j = 0; j < 4; ++j)
          bf[j] = *(const short8*)(Bsm + boff[j] + d);
        #pragma unroll
        for (int i = 0; i < 4; ++i)
          #pragma unroll
          for (int j = 0; j < 4; ++j)
            acc[i][j] = __builtin_amdgcn_mfma_f32_16x16x32_bf16(af[i], bf[j], acc[i][j], 0, 0, 0);
      }
      __syncthreads();   // protect Asm (and Bsm at kc rollover)
    }
  }

  // ---- epilogue: D col = lane&15 (p), row = q*4+reg (co) ----
  #pragma unroll
  for (int i = 0; i < 4; ++i) {
    const int co = co_t * 128 + wm * 64 + i * 16 + q * 4;
    float* orow = out + (size_t)(b * 256 + co) * 3136;
    #pragma unroll
    for (int j = 0; j < 4; ++j) {
      const int pp = p0 + wn * 64 + j * 16 + m16;
      if (pp < 3136) {
        #pragma unroll
        for (int rg = 0; rg < 4; ++rg)
          orow[(size_t)rg * 3136 + pp] = acc[i][j][rg];
      }
    }
  }
}

extern "C" void kernel_launch(void* const* d_in, const int* in_sizes, int n_in,
                              void* d_out, int out_size, void* d_ws, size_t ws_size,
                              hipStream_t stream) {
  const float* x      = (const float*)d_in[0];   // (32,256,56,56)
  const float* att_w  = (const float*)d_in[1];   // (4,256)
  const float* weight = (const float*)d_in[2];   // (4,256,256,3,3)
  float* out = (float*)d_out;                    // (32,256,56,56)

  char* ws = (char*)d_ws;
  float* pooledk       = (float*)ws;                                // 8 KB (padded stride 16)
  unsigned short* agg  = (unsigned short*)(ws + 65536);             // 37,748,736 B
  unsigned short* xpad = (unsigned short*)(ws + 65536 + 37748736);  // 55,115,776 B

  zero_pk_kernel<<<1, 256, 0, stream>>>(pooledk);
  prep_kernel<<<6272, 256, 0, stream>>>(x, att_w, xpad, pooledk);
  agg_kernel<<<dim3(256, 8), 256, 0, stream>>>(weight, pooledk, agg);
  conv_kernel<<<1600, 256, 0, stream>>>(xpad, agg, out);
}